// Round 1
// 108.575 us; speedup vs baseline: 1.0481x; 1.0481x over previous
//
#include <hip/hip_runtime.h>
#include <math.h>

#define UU 32
#define HH 5120
#define RR 160
#define NN 16

// ws layout (floats), ALL plain stores -- zero atomics, zero reliance on the
// 0xAA poison:
//   tmpP[16][32][160]  at 0       (16 split-K partials of x@W_delta)
//   BP  [16][32][16]   at 81920
//   CP  [16][32][16]   at 90112
// ssm_kernel folds the 16-way partial reduction into its LDS staging pass
// (tmpP is 320 KB total -> resident in every XCD L2; the re-read is L2-hot).
//
// R6 theory: previous structure was latency/occupancy-bound, not BW-bound.
// proj had 0.44 waves/SIMD + 80-deep device-scope fp32 atomicAdd chains
// (409k atomics); ssm had 1.25 waves/SIMD and 2 serial h-columns/thread.
// This version: atomic-free split-K partials (96 balanced proj blocks) and
// a 512-thread ssm block (2.5 waves/SIMD, one h-column per thread).
//
// NOTE (R4/R5 failure, kept from prior session): fusing proj+ssm with an
// agent-scope spin barrier regressed 115 -> 160 us. Two serial dispatches
// are the right structure on MI355X.

#define TMP_WS 0
#define BP_WS  81920
#define CP_WS  90112

// bf16 helpers: unpack is a shift (no v_cvt needed); pack uses RNE.
__device__ __forceinline__ unsigned short f2bf(float f) {
    unsigned int u = __float_as_uint(f);
    u += 0x7fffu + ((u >> 16) & 1u);       // round-to-nearest-even
    return (unsigned short)(u >> 16);
}
__device__ __forceinline__ float blo(unsigned int v) { return __uint_as_float(v << 16); }
__device__ __forceinline__ float bhi(unsigned int v) { return __uint_as_float(v & 0xffff0000u); }

__global__ __launch_bounds__(256) void proj_kernel(
    const float* __restrict__ x, const float* __restrict__ Wd,
    const float* __restrict__ WB, const float* __restrict__ WC,
    float* __restrict__ ws)
{
    __shared__ float xs[32 * 36];    // [kk][u], row padded to 36 (16B-aligned f4 reads)
    __shared__ float wt[32 * 32];    // [kk][r-tile]

    const int b = blockIdx.x;
    const int t = threadIdx.x;

    if (b < 80) {
        // ---- tmpP[s] += x[:, s*320:(s+1)*320] @ Wd-tile, NO atomics.
        // 16 K-splits x 5 r-tiles of 32. Per thread: 4 users x 1 r-col.
        const int s  = b & 15;
        const int rt = b >> 4;
        const int r0 = rt * 32;
        const int u0 = (t >> 5) * 4;     // 8 u-groups of 4
        const int r  = t & 31;
        float acc[4] = {0.f, 0.f, 0.f, 0.f};

        for (int c = 0; c < 10; c++) {   // 10 sub-chunks of 32 k
            const int k0 = s * 320 + c * 32;
            if (c) __syncthreads();      // protect LDS re-stage
            #pragma unroll
            for (int i = 0; i < 4; i++) {
                int idx = t + i * 256;
                int u = idx >> 5, kk = idx & 31;
                xs[kk * 36 + u] = x[u * HH + k0 + kk];
            }
            {   // Wd tile: 32k x 32r = 256 float4, one per thread
                int kk = t >> 3, c4 = t & 7;
                *(float4*)&wt[kk * 32 + c4 * 4] =
                    *(const float4*)(Wd + (size_t)(k0 + kk) * RR + r0 + c4 * 4);
            }
            __syncthreads();

            #pragma unroll
            for (int kk = 0; kk < 32; kk++) {
                float4 xv = *(const float4*)&xs[kk * 36 + u0];
                float wv = wt[kk * 32 + r];
                acc[0] += xv.x * wv; acc[1] += xv.y * wv;
                acc[2] += xv.z * wv; acc[3] += xv.w * wv;
            }
        }
        #pragma unroll
        for (int i = 0; i < 4; i++)
            ws[TMP_WS + s * 5120 + (u0 + i) * 160 + r0 + r] = acc[i];
    } else {
        // ---- BP[sb] = x-chunk @ W_B, CP[sb] = x-chunk @ W_C; 16 K-splits.
        // float4-vectorized x loads; WB/WC rows are 64B wave-broadcasts.
        const int sb = b - 80;
        const int k0 = sb * 320;
        const int n  = t & 15;
        const int uu = t >> 4;                 // [0,16); also handles u=uu+16
        const float* xa = x + uu * HH + k0;
        const float* xb = x + (uu + 16) * HH + k0;
        float aB0 = 0.f, aB1 = 0.f, aC0 = 0.f, aC1 = 0.f;
        #pragma unroll 2
        for (int k4 = 0; k4 < 80; k4++) {
            float4 va = *(const float4*)(xa + k4 * 4);
            float4 vb = *(const float4*)(xb + k4 * 4);
            const int kb = (k0 + k4 * 4) * NN + n;
            #define STEP(D, CMP) { \
                float wb = WB[kb + (D) * NN]; \
                float wc = WC[kb + (D) * NN]; \
                aB0 += va.CMP * wb; aB1 += vb.CMP * wb; \
                aC0 += va.CMP * wc; aC1 += vb.CMP * wc; }
            STEP(0, x) STEP(1, y) STEP(2, z) STEP(3, w)
            #undef STEP
        }
        ws[BP_WS + sb * 512 + uu * 16 + n]        = aB0;
        ws[BP_WS + sb * 512 + (uu + 16) * 16 + n] = aB1;
        ws[CP_WS + sb * 512 + uu * 16 + n]        = aC0;
        ws[CP_WS + sb * 512 + (uu + 16) * 16 + n] = aC1;
    }
}

__device__ __forceinline__ float softplusf(float v) {
    return (v > 20.f) ? v : log1pf(expf(v));
}

// One block = 16 h-columns x 32 users, 512 threads; thread (u,q) handles ONE
// h = h0+q. tmp & W_dt staged as bf16 in LDS (stride 168 bf16 = 84 words:
// 16B-aligned, conflict-free-ish b128). The 16 tmpP/BP/CP partials are
// summed during staging (L2-hot). h-state prefetched to registers first so
// the HBM read overlaps all staging + dt compute.
__global__ __launch_bounds__(512) void ssm_kernel(
    const float* __restrict__ x, const float* __restrict__ Wdt,
    const float* __restrict__ bdt, const float* __restrict__ Alog,
    const float* __restrict__ Dv, const float* __restrict__ hstate,
    const float* __restrict__ ws, float* __restrict__ y)
{
    __shared__ unsigned short tmp_b[32 * 168]; // [u][r] bf16
    __shared__ unsigned short wsl_b[16 * 168]; // [hh][r] bf16
    __shared__ float Bl[32 * 20];              // [u][n] pad 20
    __shared__ float Cl[32 * 20];
    __shared__ float an_l[16 * 20];            // [hh][n] = -exp(A_log)
    __shared__ float xl[32 * 17];              // [u][hh] pad 17
    __shared__ float bdtl[16];
    __shared__ float Dl[16];

    const int t  = threadIdx.x;
    const int h0 = blockIdx.x * 16;
    const int u  = t >> 4;                 // [0,32)
    const int q  = t & 15;                 // [0,16)

    // ---- prefetch h-state row (64B/thread, overlaps everything below)
    const float* hb = hstate + (size_t)(u * HH + h0 + q) * 16;
    float4 hv[4];
    #pragma unroll
    for (int k = 0; k < 4; k++) hv[k] = ((const float4*)hb)[k];

    // ---- stage tmp: sum 16 fp32 partials (L2-hot) -> bf16 LDS
    #pragma unroll
    for (int i = 0; i < 3; i++) {
        int idx4 = t + i * 512;
        if (idx4 < 1280) {
            float sx = 0.f, sy = 0.f, sz = 0.f, sw = 0.f;
            #pragma unroll
            for (int s = 0; s < 16; s++) {
                float4 v = ((const float4*)(ws + TMP_WS + s * 5120))[idx4];
                sx += v.x; sy += v.y; sz += v.z; sw += v.w;
            }
            int uu = idx4 / 40, r4 = idx4 % 40;
            unsigned int p0 = (unsigned int)f2bf(sx) | ((unsigned int)f2bf(sy) << 16);
            unsigned int p1 = (unsigned int)f2bf(sz) | ((unsigned int)f2bf(sw) << 16);
            *(uint2*)&tmp_b[uu * 168 + r4 * 4] = make_uint2(p0, p1);
        }
    }
    // ---- stage W_dt slice -> bf16 [hh][r] (64B coalesced rows)
    #pragma unroll
    for (int i = 0; i < 5; i++) {
        int idx = t + i * 512;
        int r = idx >> 4, hh = idx & 15;
        wsl_b[hh * 168 + r] = f2bf(Wdt[r * HH + h0 + hh]);
    }
    // ---- stage B, C (sum 16 partials), x slice
    {
        int uu = t >> 4, n = t & 15;
        float sb = 0.f, sc = 0.f;
        #pragma unroll
        for (int s = 0; s < 16; s++) {
            sb += ws[BP_WS + s * 512 + t];
            sc += ws[CP_WS + s * 512 + t];
        }
        Bl[uu * 20 + n] = sb;
        Cl[uu * 20 + n] = sc;
        xl[uu * 17 + n] = x[uu * HH + h0 + n];
    }
    // ---- stage -exp(A_log), bias, D
    if (t < 256) {
        int hh = t >> 4, n = t & 15;
        an_l[hh * 20 + n] = -expf(Alog[(h0 + hh) * 16 + n]);
    }
    if (t < 16) { bdtl[t] = bdt[h0 + t]; Dl[t] = Dv[h0 + t]; }
    __syncthreads();

    // ---- dt dot for h0+q (bf16 b128 reads, fp32 accumulate)
    const uint4* ta = (const uint4*)&tmp_b[u * 168];
    const uint4* wp = (const uint4*)&wsl_b[q * 168];
    float ae = 0.f, ao = 0.f;
    #pragma unroll
    for (int c = 0; c < 20; c++) {
        uint4 av = ta[c];
        uint4 wv = wp[c];
        #define MAC(X) \
            ae += blo(av.X) * blo(wv.X); ao += bhi(av.X) * bhi(wv.X);
        MAC(x) MAC(y) MAC(z) MAC(w)
        #undef MAC
    }
    const float dt = softplusf(bdtl[q] + (ae + ao));

    // ---- SSM update + output reduction
    const float xv = xl[u * 17 + q];
    const float K  = dt * xv;
    float yv = xv * Dl[q];
    #pragma unroll
    for (int qq = 0; qq < 4; qq++) {
        float4 h4 = hv[qq];
        float4 b4 = *(const float4*)&Bl[u * 20 + qq * 4];
        float4 c4 = *(const float4*)&Cl[u * 20 + qq * 4];
        float4 a4 = *(const float4*)&an_l[q * 20 + qq * 4];
        yv += (expf(dt * a4.x) * h4.x + K * b4.x) * c4.x;
        yv += (expf(dt * a4.y) * h4.y + K * b4.y) * c4.y;
        yv += (expf(dt * a4.z) * h4.z + K * b4.z) * c4.z;
        yv += (expf(dt * a4.w) * h4.w + K * b4.w) * c4.w;
    }
    y[u * HH + h0 + q] = yv;
}

extern "C" void kernel_launch(void* const* d_in, const int* in_sizes, int n_in,
                              void* d_out, int out_size, void* d_ws, size_t ws_size,
                              hipStream_t stream) {
    const float* x    = (const float*)d_in[0];
    const float* Wd   = (const float*)d_in[1];
    const float* Wdt  = (const float*)d_in[2];
    const float* bdt  = (const float*)d_in[3];
    const float* WB   = (const float*)d_in[4];
    const float* WC   = (const float*)d_in[5];
    const float* Alog = (const float*)d_in[6];
    const float* Dv   = (const float*)d_in[7];
    const float* hst  = (const float*)d_in[8];
    float* y  = (float*)d_out;
    float* ws = (float*)d_ws;

    proj_kernel<<<96, 256, 0, stream>>>(x, Wd, WB, WC, ws);
    ssm_kernel<<<320, 512, 0, stream>>>(x, Wdt, bdt, Alog, Dv, hst, ws, y);
}